// Round 7
// baseline (770.743 us; speedup 1.0000x reference)
//
#include <hip/hip_runtime.h>
#include <hip/hip_bf16.h>
#include <math.h>

#define HD 128   // hidden dim = H*C
#define NH 4     // heads
#define CC 32    // channels per head

typedef __attribute__((ext_vector_type(8))) short short8;
typedef __attribute__((ext_vector_type(4))) float f32x4;

__device__ __forceinline__ float leaky(float x) { return x > 0.f ? x : 0.01f * x; }

// f32 -> bf16 round-to-nearest-even (finite values)
__device__ __forceinline__ ushort bf16_rne(float f) {
    unsigned u = __float_as_uint(f);
    return (ushort)((u + 0x7fffu + ((u >> 16) & 1u)) >> 16);
}
__device__ __forceinline__ float bf16_f(ushort h) {
    return __uint_as_float(((unsigned)h) << 16);
}

// Wfrag layout: [mg(12)][ct(8)][kk(4)][lane(64)][j(8)] ushort, hi half then lo
// half at +WFRAG_HALF. mg = layer*4 + mat. B-frag mapping (16x16x32):
// col = ct*16+(lane&15), k = kk*32+(lane>>4)*8+j.   (verified: r5 passed)
#define WFRAG_HALF (12 * 32 * 64 * 8)

// ---------------------------------------------------------------------------
// Convert W (f32, [3][128][128] x 4 matrices) into bf16 hi/lo B-fragments.
// ---------------------------------------------------------------------------
__global__ __launch_bounds__(256) void conv_w(
    const float* __restrict__ Wq, const float* __restrict__ Wk,
    const float* __restrict__ Wv, const float* __restrict__ Wsk,
    ushort* __restrict__ frag)
{
    int tid = blockIdx.x * 256 + threadIdx.x;
    if (tid >= 12 * 8 * 4 * 64) return;
    int lane = tid & 63;
    int kk = (tid >> 6) & 3;
    int ct = (tid >> 8) & 7;
    int mg = tid >> 11;            // 0..11
    int l = mg >> 2, m = mg & 3;
    const float* src = ((m == 0) ? Wq : (m == 1) ? Wk : (m == 2) ? Wv : Wsk)
                       + (size_t)l * HD * HD;
    int col = ct * 16 + (lane & 15);
    int k0 = kk * 32 + (lane >> 4) * 8;
    ushort* dst = frag + (size_t)tid * 8;
#pragma unroll
    for (int j = 0; j < 8; ++j) {
        float w = src[(size_t)(k0 + j) * HD + col];
        ushort h = bf16_rne(w);
        dst[j] = h;
        dst[WFRAG_HALF + j] = bf16_rne(w - bf16_f(h));
    }
}

// ---------------------------------------------------------------------------
// MFMA GEMM, split-bf16 (hh+hl+lh). 512 threads = 8 waves; wave = col-tile ct.
// 128 rows/block staged as hi/lo bf16 in swizzled LDS (64 KB). W-fragments for
// the wave's ct are loaded ONCE per mat into registers (32 VGPRs), so the
// inner loop is pure {ds_read_b128 + MFMA} — no global latency in the chain.
// 3 accumulator chains (hh/hl/lh) keep dependent-MFMA chains 4 deep.
// blockIdx.y selects mats {2y, 2y+1}.
// ---------------------------------------------------------------------------
__global__ __launch_bounds__(512) void gemm4_mfma(
    const float* __restrict__ X, const ushort* __restrict__ Wfrag,
    const float* __restrict__ bq, const float* __restrict__ bk,
    const float* __restrict__ bv, const float* __restrict__ bsk,
    float* __restrict__ Oq, float* __restrict__ Ok,
    float* __restrict__ Ov, float* __restrict__ Osk,
    int layer, int N)
{
    __shared__ __align__(16) ushort Xh[128 * HD];
    __shared__ __align__(16) ushort Xl[128 * HD];

    int t = threadIdx.x;
    int row0 = blockIdx.x * 128;

    // ---- stage X tile as hi/lo bf16, swizzled: byte ^= (row&7)<<4 ----
#pragma unroll
    for (int i = 0; i < 8; ++i) {
        int idx = t + i * 512;           // 0..4095
        int r = idx >> 5;                // 0..127
        int c4 = (idx & 31) * 4;         // first k of this float4
        int gr = row0 + r;
        float4 xv = (gr < N) ? *(const float4*)(X + (size_t)gr * HD + c4)
                             : make_float4(0.f, 0.f, 0.f, 0.f);
        ushort h0 = bf16_rne(xv.x), h1 = bf16_rne(xv.y),
               h2 = bf16_rne(xv.z), h3 = bf16_rne(xv.w);
        ushort l0 = bf16_rne(xv.x - bf16_f(h0)), l1 = bf16_rne(xv.y - bf16_f(h1)),
               l2 = bf16_rne(xv.z - bf16_f(h2)), l3 = bf16_rne(xv.w - bf16_f(h3));
        int off = r * 256 + c4 * 2;                 // byte offset, 8B-aligned
        int swz = off ^ ((r & 7) << 4);
        *(ushort4*)((char*)Xh + swz) = make_ushort4(h0, h1, h2, h3);
        *(ushort4*)((char*)Xl + swz) = make_ushort4(l0, l1, l2, l3);
    }
    __syncthreads();

    int ct = t >> 6;                 // wave id = col tile 0..7
    int lane = t & 63;
    int col16 = lane & 15;
    int quad = lane >> 4;

#pragma unroll
    for (int mm = 0; mm < 2; ++mm) {
        int mat = blockIdx.y * 2 + mm;
        const float* b = (mat == 0) ? bq : (mat == 1) ? bk : (mat == 2) ? bv : bsk;
        float* O = (mat == 0) ? Oq : (mat == 1) ? Ok : (mat == 2) ? Ov : Osk;
        int mg = layer * 4 + mat;

        // ---- load this wave's W fragments once (coalesced, L2-hit) ----
        short8 bh[4], bl[4];
#pragma unroll
        for (int kk = 0; kk < 4; ++kk) {
            const ushort* wp = Wfrag + ((size_t)((mg * 8 + ct) * 4 + kk) * 64 + lane) * 8;
            bh[kk] = *(const short8*)wp;
            bl[kk] = *(const short8*)(wp + WFRAG_HALF);
        }
        float bcol = b[ct * 16 + col16];

#pragma unroll
        for (int mt = 0; mt < 8; ++mt) {
            int arow = mt * 16 + col16;          // A row for this lane
            int abase = arow * 256;
            int aswz = (arow & 7) << 4;
            f32x4 a0 = {0.f, 0.f, 0.f, 0.f};
            f32x4 a1 = {0.f, 0.f, 0.f, 0.f};
            f32x4 a2 = {0.f, 0.f, 0.f, 0.f};
#pragma unroll
            for (int kk = 0; kk < 4; ++kk) {
                int koff = abase + kk * 64 + quad * 16;   // bytes
                short8 ah = *(const short8*)((const char*)Xh + (koff ^ aswz));
                short8 al = *(const short8*)((const char*)Xl + (koff ^ aswz));
                a0 = __builtin_amdgcn_mfma_f32_16x16x32_bf16(ah, bh[kk], a0, 0, 0, 0);
                a1 = __builtin_amdgcn_mfma_f32_16x16x32_bf16(ah, bl[kk], a1, 0, 0, 0);
                a2 = __builtin_amdgcn_mfma_f32_16x16x32_bf16(al, bh[kk], a2, 0, 0, 0);
            }
            // C/D: col = lane&15, row = quad*4 + i (m89-verified)
            int orow0 = row0 + mt * 16 + quad * 4;
#pragma unroll
            for (int i = 0; i < 4; ++i) {
                int r = orow0 + i;
                if (r < N)
                    O[(size_t)r * HD + ct * 16 + col16] = a0[i] + a1[i] + a2[i] + bcol;
            }
        }
    }
}

// ---------------------------------------------------------------------------
// CSR build step 1: deg[dst]++ per edge
// ---------------------------------------------------------------------------
__global__ __launch_bounds__(256) void count_deg(
    const int* __restrict__ ei, int* __restrict__ deg, int E)
{
    int e = blockIdx.x * 256 + threadIdx.x;
    if (e < E) atomicAdd(&deg[ei[E + e]], 1);
}

// ---------------------------------------------------------------------------
// CSR build step 2: exclusive scan of deg -> off (N+1), duplicate into cursor.
// ---------------------------------------------------------------------------
__global__ __launch_bounds__(1024) void scan_kernel(
    const int* __restrict__ deg, int* __restrict__ off,
    int* __restrict__ cursor, int N)
{
    __shared__ int wsum[16];
    __shared__ int carry_s;
    int tid = threadIdx.x;
    int lane = tid & 63;
    int w = tid >> 6;
    if (tid == 0) carry_s = 0;
    __syncthreads();
    for (int base = 0; base < N; base += 1024) {
        int idx = base + tid;
        int x = (idx < N) ? deg[idx] : 0;
        int val = x;
#pragma unroll
        for (int s = 1; s < 64; s <<= 1) {
            int t = __shfl_up(val, s);
            if (lane >= s) val += t;
        }
        if (lane == 63) wsum[w] = val;
        __syncthreads();
        if (w == 0) {
            int t = (lane < 16) ? wsum[lane] : 0;
#pragma unroll
            for (int s = 1; s < 16; s <<= 1) {
                int u = __shfl_up(t, s);
                if (lane >= s) t += u;
            }
            if (lane < 16) wsum[lane] = t;  // inclusive wave totals
        }
        __syncthreads();
        int carry = carry_s;
        int wexcl = (w > 0) ? wsum[w - 1] : 0;
        int excl = carry + wexcl + (val - x);
        if (idx < N) { off[idx] = excl; cursor[idx] = excl; }
        __syncthreads();
        if (tid == 0) carry_s = carry + wsum[15];
        __syncthreads();
    }
    if (threadIdx.x == 0) off[N] = carry_s;
}

// ---------------------------------------------------------------------------
// CSR build step 3: scatter edge meta {src, ea0, ea1} into dst-grouped slots
// ---------------------------------------------------------------------------
__global__ __launch_bounds__(256) void scatter_edges(
    const int* __restrict__ ei, const float* __restrict__ ea,
    int* __restrict__ cursor, float4* __restrict__ meta, int E)
{
    int e = blockIdx.x * 256 + threadIdx.x;
    if (e >= E) return;
    int dst = ei[E + e];
    int pos = atomicAdd(&cursor[dst], 1);
    meta[pos] = make_float4(__int_as_float(ei[e]), ea[2 * e], ea[2 * e + 1], 0.f);
}

// ---------------------------------------------------------------------------
// Flash-style fused attention: one wave per dst node. Online softmax over the
// node's incoming edges; no atomics, no alpha materialization. Epilogue fuses
// skip + leakyReLU. lane -> 2 channels (c = 2*lane), head = lane>>4.
// ---------------------------------------------------------------------------
__global__ __launch_bounds__(256) void fused_attn(
    const float* __restrict__ q, const float* __restrict__ k,
    const float* __restrict__ v, const float* __restrict__ skip,
    const int* __restrict__ off, const float4* __restrict__ meta,
    const float* __restrict__ We, float* __restrict__ hout, int N)
{
    int wid = (int)((blockIdx.x * 256 + threadIdx.x) >> 6);  // dst node
    int lane = threadIdx.x & 63;
    if (wid >= N) return;
    int c = lane * 2;

    float2 w0 = *(const float2*)(We + c);        // We row 0, this lane's 2 cols
    float2 w1 = *(const float2*)(We + HD + c);   // We row 1
    float2 q2 = *(const float2*)(q + (size_t)wid * HD + c);

    float m = -INFINITY, s = 0.f;
    float ox = 0.f, oy = 0.f;

    int beg = off[wid], end = off[wid + 1];
    for (int j = beg; j < end; ++j) {
        float4 md = meta[j];                      // broadcast (uniform addr)
        int src = __float_as_int(md.x);
        float ex = md.y * w0.x + md.z * w1.x;
        float ey = md.y * w0.y + md.z * w1.y;
        float2 kv = *(const float2*)(k + (size_t)src * HD + c);
        float2 vv = *(const float2*)(v + (size_t)src * HD + c);
        float p = q2.x * (kv.x + ex) + q2.y * (kv.y + ey);
        p += __shfl_xor(p, 1);
        p += __shfl_xor(p, 2);
        p += __shfl_xor(p, 4);
        p += __shfl_xor(p, 8);
        p *= 0.17677669529663687f;               // 1/sqrt(32)
        float mn = fmaxf(m, p);
        float scale = __expf(m - mn);            // first iter: exp(-inf)=0
        float pe = __expf(p - mn);
        s = s * scale + pe;
        ox = ox * scale + pe * (vv.x + ex);
        oy = oy * scale + pe * (vv.y + ey);
        m = mn;
    }

    float inv = 1.f / (s + 1e-16f);              // deg==0: o=0 -> skip only
    float2 sk = *(const float2*)(skip + (size_t)wid * HD + c);
    float2 hv;
    hv.x = leaky(ox * inv + sk.x);
    hv.y = leaky(oy * inv + sk.y);
    *(float2*)(hout + (size_t)wid * HD + c) = hv;
}

// ---------------------------------------------------------------------------
// emb = leaky(h @ W1 + b1)   (N x 128 @ 128 x 32)
// ---------------------------------------------------------------------------
__global__ __launch_bounds__(256) void emb_kernel(
    const float* __restrict__ h, const float* __restrict__ W1,
    const float* __restrict__ b1, float* __restrict__ emb, int N)
{
    int i = blockIdx.x * 256 + threadIdx.x;
    if (i >= N * CC) return;
    int row = i >> 5, col = i & 31;
    const float* hr = h + (size_t)row * HD;
    float acc = 0.f;
#pragma unroll 4
    for (int k = 0; k < HD; ++k) acc += hr[k] * W1[k * CC + col];
    emb[i] = leaky(acc + b1[col]);
}

// ---------------------------------------------------------------------------
// logits = emb @ W2 + b2; out = log_softmax(logits) per row (8 cols).
// ---------------------------------------------------------------------------
__global__ __launch_bounds__(256) void logits_kernel(
    const float* __restrict__ emb, const float* __restrict__ W2,
    const float* __restrict__ b2, float* __restrict__ out, int N)
{
    int i = blockIdx.x * 256 + threadIdx.x;
    int row = i >> 3, col = i & 7;
    if (row >= N) return;
    const float* er = emb + (size_t)row * CC;
    float acc = b2[col];
#pragma unroll
    for (int k = 0; k < CC; ++k) acc += er[k] * W2[k * 8 + col];
    float mx = acc;
    mx = fmaxf(mx, __shfl_xor(mx, 1));
    mx = fmaxf(mx, __shfl_xor(mx, 2));
    mx = fmaxf(mx, __shfl_xor(mx, 4));
    float ex = expf(acc - mx);
    float sm = ex;
    sm += __shfl_xor(sm, 1);
    sm += __shfl_xor(sm, 2);
    sm += __shfl_xor(sm, 4);
    out[i] = acc - mx - logf(sm);
}

extern "C" void kernel_launch(void* const* d_in, const int* in_sizes, int n_in,
                              void* d_out, int out_size, void* d_ws, size_t ws_size,
                              hipStream_t stream)
{
    const float* x  = (const float*)d_in[0];
    const int*   ei = (const int*)d_in[1];
    const float* ea = (const float*)d_in[2];
    const float* Wq = (const float*)d_in[3];
    const float* bq = (const float*)d_in[4];
    const float* Wk = (const float*)d_in[5];
    const float* bk = (const float*)d_in[6];
    const float* Wv = (const float*)d_in[7];
    const float* bv = (const float*)d_in[8];
    const float* We = (const float*)d_in[9];
    const float* Ws = (const float*)d_in[10];
    const float* bs = (const float*)d_in[11];
    const float* W1 = (const float*)d_in[12];
    const float* b1 = (const float*)d_in[13];
    const float* W2 = (const float*)d_in[14];
    const float* b2 = (const float*)d_in[15];

    int N = in_sizes[0] / HD;
    int E = in_sizes[1] / 2;

    float* ws = (float*)d_ws;
    size_t nd = (size_t)N * HD;
    float* hbuf = ws;
    float* qbuf = ws + nd;
    float* kbuf = ws + 2 * nd;
    float* vbuf = ws + 3 * nd;
    float* sbuf = ws + 4 * nd;
    float4* meta = (float4*)(ws + 5 * nd);           // E float4
    int* deg    = (int*)(ws + 5 * nd + 4 * (size_t)E);
    int* off    = deg + N;                            // N+1
    int* cursor = off + N + 1;                        // N
    size_t frag_byte = (((5 * nd + 4 * (size_t)E) + (size_t)(3 * N + 1)) * 4 + 15)
                       & ~(size_t)15;
    ushort* Wfrag = (ushort*)((char*)d_ws + frag_byte);

    int gemm_gx = (N + 127) / 128;
    int edge_gx = (E + 255) / 256;
    int attn_gx = (N + 3) / 4;

    // ---- CSR build + weight fragment conversion (once per call) ----
    hipMemsetAsync(deg, 0, (size_t)N * sizeof(int), stream);
    count_deg<<<edge_gx, 256, 0, stream>>>(ei, deg, E);
    scan_kernel<<<1, 1024, 0, stream>>>(deg, off, cursor, N);
    scatter_edges<<<edge_gx, 256, 0, stream>>>(ei, ea, cursor, meta, E);
    conv_w<<<(12 * 8 * 4 * 64 + 255) / 256, 256, 0, stream>>>(Wq, Wk, Wv, Ws, Wfrag);

    for (int l = 0; l < 3; ++l) {
        const float* cur = (l == 0) ? x : hbuf;
        const float* Wel = We + (size_t)l * 2 * HD;

        gemm4_mfma<<<dim3(gemm_gx, 2), 512, 0, stream>>>(
            cur, Wfrag,
            bq + (size_t)l * HD, bk + (size_t)l * HD,
            bv + (size_t)l * HD, bs + (size_t)l * HD,
            qbuf, kbuf, vbuf, sbuf, l, N);

        fused_attn<<<attn_gx, 256, 0, stream>>>(
            qbuf, kbuf, vbuf, sbuf, off, meta, Wel, hbuf, N);
    }

    // head: emb = leaky(h@W1+b1) -> reuse kbuf; logits+log_softmax -> d_out
    emb_kernel<<<(N * CC + 255) / 256, 256, 0, stream>>>(hbuf, W1, b1, kbuf, N);
    logits_kernel<<<(N * 8 + 255) / 256, 256, 0, stream>>>(kbuf, W2, b2, (float*)d_out, N);
}

// Round 8
// 608.858 us; speedup vs baseline: 1.2659x; 1.2659x over previous
//
#include <hip/hip_runtime.h>
#include <hip/hip_bf16.h>
#include <math.h>

#define HD 128   // hidden dim = H*C
#define NH 4     // heads
#define CC 32    // channels per head

typedef __attribute__((ext_vector_type(8))) short short8;
typedef __attribute__((ext_vector_type(4))) float f32x4;

__device__ __forceinline__ float leaky(float x) { return x > 0.f ? x : 0.01f * x; }

// f32 -> bf16 round-to-nearest-even (finite values)
__device__ __forceinline__ ushort bf16_rne(float f) {
    unsigned u = __float_as_uint(f);
    return (ushort)((u + 0x7fffu + ((u >> 16) & 1u)) >> 16);
}
__device__ __forceinline__ float bf16_f(ushort h) {
    return __uint_as_float(((unsigned)h) << 16);
}

// Wfrag layout: [mg(12)][ct(8)][kk(4)][lane(64)][j(8)] ushort, hi half then lo
// half at +WFRAG_HALF. mg = layer*4 + mat. B-frag mapping (16x16x32):
// col = ct*16+(lane&15), k = kk*32+(lane>>4)*8+j.   (verified: r5/r7 passed)
#define WFRAG_HALF (12 * 32 * 64 * 8)

// ---------------------------------------------------------------------------
// Convert W (f32, [3][128][128] x 4 matrices) into bf16 hi/lo B-fragments.
// ---------------------------------------------------------------------------
__global__ __launch_bounds__(256) void conv_w(
    const float* __restrict__ Wq, const float* __restrict__ Wk,
    const float* __restrict__ Wv, const float* __restrict__ Wsk,
    ushort* __restrict__ frag)
{
    int tid = blockIdx.x * 256 + threadIdx.x;
    if (tid >= 12 * 8 * 4 * 64) return;
    int lane = tid & 63;
    int kk = (tid >> 6) & 3;
    int ct = (tid >> 8) & 7;
    int mg = tid >> 11;            // 0..11
    int l = mg >> 2, m = mg & 3;
    const float* src = ((m == 0) ? Wq : (m == 1) ? Wk : (m == 2) ? Wv : Wsk)
                       + (size_t)l * HD * HD;
    int col = ct * 16 + (lane & 15);
    int k0 = kk * 32 + (lane >> 4) * 8;
    ushort* dst = frag + (size_t)tid * 8;
#pragma unroll
    for (int j = 0; j < 8; ++j) {
        float w = src[(size_t)(k0 + j) * HD + col];
        ushort h = bf16_rne(w);
        dst[j] = h;
        dst[WFRAG_HALF + j] = bf16_rne(w - bf16_f(h));
    }
}

// ---------------------------------------------------------------------------
// MFMA GEMM, split-bf16 (hh+hl+lh). 512 threads = 8 waves.
// Block = 64 rows. Wave = (p, h): p in 0..3 owns cols p*32..p*32+31 (two
// 16-col MFMA tiles), h in 0..1 owns rows h*32..h*32+31 (two 16-row tiles).
// W-fragments for the wave's 2 col-tiles live in registers (64 VGPRs).
// Epilogue: per 16-row tile, acc is bounced through a wave-PRIVATE LDS
// scratch (no barriers) and stored as float4/lane, 8 lanes/row => every
// store instruction writes full aligned 128B lines from ONE wave. This is
// the r7 fix: r7's 64B-half-lines from drifting waves caused RFO fetch of
// the output (FETCH ~= +102MB) and ~2.6x write amplification.
// blockIdx.y selects mats {2y, 2y+1}.
// ---------------------------------------------------------------------------
__global__ __launch_bounds__(512) void gemm4_mfma(
    const float* __restrict__ X, const ushort* __restrict__ Wfrag,
    const float* __restrict__ bq, const float* __restrict__ bk,
    const float* __restrict__ bv, const float* __restrict__ bsk,
    float* __restrict__ Oq, float* __restrict__ Ok,
    float* __restrict__ Ov, float* __restrict__ Osk,
    int layer, int N)
{
    __shared__ __align__(16) ushort Xh[64 * HD];   // 16 KB
    __shared__ __align__(16) ushort Xl[64 * HD];   // 16 KB
    __shared__ __align__(16) float  Ot[8][16 * 36]; // 18 KB wave-private scratch

    int t = threadIdx.x;
    int row0 = blockIdx.x * 64;

    // ---- stage X tile as hi/lo bf16, swizzled: byte ^= (row&7)<<4 ----
#pragma unroll
    for (int i = 0; i < 4; ++i) {
        int idx = t + i * 512;           // 0..2047
        int r = idx >> 5;                // 0..63
        int c4 = (idx & 31) * 4;         // first k of this float4
        int gr = row0 + r;
        float4 xv = (gr < N) ? *(const float4*)(X + (size_t)gr * HD + c4)
                             : make_float4(0.f, 0.f, 0.f, 0.f);
        ushort h0 = bf16_rne(xv.x), h1 = bf16_rne(xv.y),
               h2 = bf16_rne(xv.z), h3 = bf16_rne(xv.w);
        ushort l0 = bf16_rne(xv.x - bf16_f(h0)), l1 = bf16_rne(xv.y - bf16_f(h1)),
               l2 = bf16_rne(xv.z - bf16_f(h2)), l3 = bf16_rne(xv.w - bf16_f(h3));
        int off = r * 256 + c4 * 2;                 // byte offset, 8B-aligned
        int swz = off ^ ((r & 7) << 4);
        *(ushort4*)((char*)Xh + swz) = make_ushort4(h0, h1, h2, h3);
        *(ushort4*)((char*)Xl + swz) = make_ushort4(l0, l1, l2, l3);
    }
    __syncthreads();

    int w = t >> 6;                  // wave id
    int p = w & 3;                   // col pair: cols p*32..p*32+31
    int h = w >> 2;                  // row half: rows h*32..h*32+31
    int lane = t & 63;
    int col16 = lane & 15;
    int quad = lane >> 4;
    float* scratch = Ot[w];

#pragma unroll
    for (int mm = 0; mm < 2; ++mm) {
        int mat = blockIdx.y * 2 + mm;
        const float* b = (mat == 0) ? bq : (mat == 1) ? bk : (mat == 2) ? bv : bsk;
        float* O = (mat == 0) ? Oq : (mat == 1) ? Ok : (mat == 2) ? Ov : Osk;
        int mg = layer * 4 + mat;

        // ---- load this wave's 2 col-tiles' W fragments into registers ----
        short8 bh[2][4], bl[2][4];
#pragma unroll
        for (int cl = 0; cl < 2; ++cl) {
            int ct = p * 2 + cl;
#pragma unroll
            for (int kk = 0; kk < 4; ++kk) {
                const ushort* wp = Wfrag + ((size_t)((mg * 8 + ct) * 4 + kk) * 64 + lane) * 8;
                bh[cl][kk] = *(const short8*)wp;
                bl[cl][kk] = *(const short8*)(wp + WFRAG_HALF);
            }
        }
        float bcol0 = b[(p * 2 + 0) * 16 + col16];
        float bcol1 = b[(p * 2 + 1) * 16 + col16];

#pragma unroll
        for (int mtl = 0; mtl < 2; ++mtl) {
            int arow = h * 32 + mtl * 16 + col16;    // A row for this lane
            int abase = arow * 256;
            int aswz = (arow & 7) << 4;
            f32x4 c0a = {0.f,0.f,0.f,0.f}, c0b = {0.f,0.f,0.f,0.f}, c0c = {0.f,0.f,0.f,0.f};
            f32x4 c1a = {0.f,0.f,0.f,0.f}, c1b = {0.f,0.f,0.f,0.f}, c1c = {0.f,0.f,0.f,0.f};
#pragma unroll
            for (int kk = 0; kk < 4; ++kk) {
                int koff = abase + kk * 64 + quad * 16;   // bytes
                short8 ah = *(const short8*)((const char*)Xh + (koff ^ aswz));
                short8 al = *(const short8*)((const char*)Xl + (koff ^ aswz));
                c0a = __builtin_amdgcn_mfma_f32_16x16x32_bf16(ah, bh[0][kk], c0a, 0, 0, 0);
                c0b = __builtin_amdgcn_mfma_f32_16x16x32_bf16(ah, bl[0][kk], c0b, 0, 0, 0);
                c0c = __builtin_amdgcn_mfma_f32_16x16x32_bf16(al, bh[0][kk], c0c, 0, 0, 0);
                c1a = __builtin_amdgcn_mfma_f32_16x16x32_bf16(ah, bh[1][kk], c1a, 0, 0, 0);
                c1b = __builtin_amdgcn_mfma_f32_16x16x32_bf16(ah, bl[1][kk], c1b, 0, 0, 0);
                c1c = __builtin_amdgcn_mfma_f32_16x16x32_bf16(al, bh[1][kk], c1c, 0, 0, 0);
            }
            // ---- epilogue: C/D col=lane&15, row=quad*4+i (m89-verified) ----
            // stage 16x32 tile into wave-private scratch (stride 36 floats)
#pragma unroll
            for (int i = 0; i < 4; ++i) {
                int rr = quad * 4 + i;
                scratch[rr * 36 + col16]      = c0a[i] + c0b[i] + c0c[i] + bcol0;
                scratch[rr * 36 + 16 + col16] = c1a[i] + c1b[i] + c1c[i] + bcol1;
            }
            // read back transposed: lane -> row lane>>3, 16B at (lane&7)*4;
            // each store instr = 8 rows x full 128B aligned line
#pragma unroll
            for (int s = 0; s < 2; ++s) {
                int row = s * 8 + (lane >> 3);
                int c4 = (lane & 7) * 4;
                float4 v = *(const float4*)(&scratch[row * 36 + c4]);
                int gr = row0 + h * 32 + mtl * 16 + row;
                if (gr < N)
                    *(float4*)(O + (size_t)gr * HD + p * 32 + c4) = v;
            }
        }
    }
}

// ---------------------------------------------------------------------------
// CSR build step 1: deg[dst]++ per edge
// ---------------------------------------------------------------------------
__global__ __launch_bounds__(256) void count_deg(
    const int* __restrict__ ei, int* __restrict__ deg, int E)
{
    int e = blockIdx.x * 256 + threadIdx.x;
    if (e < E) atomicAdd(&deg[ei[E + e]], 1);
}

// ---------------------------------------------------------------------------
// CSR build step 2: exclusive scan of deg -> off (N+1), duplicate into cursor.
// ---------------------------------------------------------------------------
__global__ __launch_bounds__(1024) void scan_kernel(
    const int* __restrict__ deg, int* __restrict__ off,
    int* __restrict__ cursor, int N)
{
    __shared__ int wsum[16];
    __shared__ int carry_s;
    int tid = threadIdx.x;
    int lane = tid & 63;
    int w = tid >> 6;
    if (tid == 0) carry_s = 0;
    __syncthreads();
    for (int base = 0; base < N; base += 1024) {
        int idx = base + tid;
        int x = (idx < N) ? deg[idx] : 0;
        int val = x;
#pragma unroll
        for (int s = 1; s < 64; s <<= 1) {
            int t = __shfl_up(val, s);
            if (lane >= s) val += t;
        }
        if (lane == 63) wsum[w] = val;
        __syncthreads();
        if (w == 0) {
            int t = (lane < 16) ? wsum[lane] : 0;
#pragma unroll
            for (int s = 1; s < 16; s <<= 1) {
                int u = __shfl_up(t, s);
                if (lane >= s) t += u;
            }
            if (lane < 16) wsum[lane] = t;  // inclusive wave totals
        }
        __syncthreads();
        int carry = carry_s;
        int wexcl = (w > 0) ? wsum[w - 1] : 0;
        int excl = carry + wexcl + (val - x);
        if (idx < N) { off[idx] = excl; cursor[idx] = excl; }
        __syncthreads();
        if (tid == 0) carry_s = carry + wsum[15];
        __syncthreads();
    }
    if (threadIdx.x == 0) off[N] = carry_s;
}

// ---------------------------------------------------------------------------
// CSR build step 3: scatter edge meta {src, ea0, ea1} into dst-grouped slots
// ---------------------------------------------------------------------------
__global__ __launch_bounds__(256) void scatter_edges(
    const int* __restrict__ ei, const float* __restrict__ ea,
    int* __restrict__ cursor, float4* __restrict__ meta, int E)
{
    int e = blockIdx.x * 256 + threadIdx.x;
    if (e >= E) return;
    int dst = ei[E + e];
    int pos = atomicAdd(&cursor[dst], 1);
    meta[pos] = make_float4(__int_as_float(ei[e]), ea[2 * e], ea[2 * e + 1], 0.f);
}

// ---------------------------------------------------------------------------
// Flash-style fused attention: one wave per dst node. Online softmax over the
// node's incoming edges; no atomics, no alpha materialization. Epilogue fuses
// skip + leakyReLU. lane -> 2 channels (c = 2*lane), head = lane>>4.
// ---------------------------------------------------------------------------
__global__ __launch_bounds__(256) void fused_attn(
    const float* __restrict__ q, const float* __restrict__ k,
    const float* __restrict__ v, const float* __restrict__ skip,
    const int* __restrict__ off, const float4* __restrict__ meta,
    const float* __restrict__ We, float* __restrict__ hout, int N)
{
    int wid = (int)((blockIdx.x * 256 + threadIdx.x) >> 6);  // dst node
    int lane = threadIdx.x & 63;
    if (wid >= N) return;
    int c = lane * 2;

    float2 w0 = *(const float2*)(We + c);        // We row 0, this lane's 2 cols
    float2 w1 = *(const float2*)(We + HD + c);   // We row 1
    float2 q2 = *(const float2*)(q + (size_t)wid * HD + c);

    float m = -INFINITY, s = 0.f;
    float ox = 0.f, oy = 0.f;

    int beg = off[wid], end = off[wid + 1];
    for (int j = beg; j < end; ++j) {
        float4 md = meta[j];                      // broadcast (uniform addr)
        int src = __float_as_int(md.x);
        float ex = md.y * w0.x + md.z * w1.x;
        float ey = md.y * w0.y + md.z * w1.y;
        float2 kv = *(const float2*)(k + (size_t)src * HD + c);
        float2 vv = *(const float2*)(v + (size_t)src * HD + c);
        float p = q2.x * (kv.x + ex) + q2.y * (kv.y + ey);
        p += __shfl_xor(p, 1);
        p += __shfl_xor(p, 2);
        p += __shfl_xor(p, 4);
        p += __shfl_xor(p, 8);
        p *= 0.17677669529663687f;               // 1/sqrt(32)
        float mn = fmaxf(m, p);
        float scale = __expf(m - mn);            // first iter: exp(-inf)=0
        float pe = __expf(p - mn);
        s = s * scale + pe;
        ox = ox * scale + pe * (vv.x + ex);
        oy = oy * scale + pe * (vv.y + ey);
        m = mn;
    }

    float inv = 1.f / (s + 1e-16f);              // deg==0: o=0 -> skip only
    float2 sk = *(const float2*)(skip + (size_t)wid * HD + c);
    float2 hv;
    hv.x = leaky(ox * inv + sk.x);
    hv.y = leaky(oy * inv + sk.y);
    *(float2*)(hout + (size_t)wid * HD + c) = hv;
}

// ---------------------------------------------------------------------------
// emb = leaky(h @ W1 + b1)   (N x 128 @ 128 x 32)
// ---------------------------------------------------------------------------
__global__ __launch_bounds__(256) void emb_kernel(
    const float* __restrict__ h, const float* __restrict__ W1,
    const float* __restrict__ b1, float* __restrict__ emb, int N)
{
    int i = blockIdx.x * 256 + threadIdx.x;
    if (i >= N * CC) return;
    int row = i >> 5, col = i & 31;
    const float* hr = h + (size_t)row * HD;
    float acc = 0.f;
#pragma unroll 4
    for (int k = 0; k < HD; ++k) acc += hr[k] * W1[k * CC + col];
    emb[i] = leaky(acc + b1[col]);
}

// ---------------------------------------------------------------------------
// logits = emb @ W2 + b2; out = log_softmax(logits) per row (8 cols).
// ---------------------------------------------------------------------------
__global__ __launch_bounds__(256) void logits_kernel(
    const float* __restrict__ emb, const float* __restrict__ W2,
    const float* __restrict__ b2, float* __restrict__ out, int N)
{
    int i = blockIdx.x * 256 + threadIdx.x;
    int row = i >> 3, col = i & 7;
    if (row >= N) return;
    const float* er = emb + (size_t)row * CC;
    float acc = b2[col];
#pragma unroll
    for (int k = 0; k < CC; ++k) acc += er[k] * W2[k * 8 + col];
    float mx = acc;
    mx = fmaxf(mx, __shfl_xor(mx, 1));
    mx = fmaxf(mx, __shfl_xor(mx, 2));
    mx = fmaxf(mx, __shfl_xor(mx, 4));
    float ex = expf(acc - mx);
    float sm = ex;
    sm += __shfl_xor(sm, 1);
    sm += __shfl_xor(sm, 2);
    sm += __shfl_xor(sm, 4);
    out[i] = acc - mx - logf(sm);
}

extern "C" void kernel_launch(void* const* d_in, const int* in_sizes, int n_in,
                              void* d_out, int out_size, void* d_ws, size_t ws_size,
                              hipStream_t stream)
{
    const float* x  = (const float*)d_in[0];
    const int*   ei = (const int*)d_in[1];
    const float* ea = (const float*)d_in[2];
    const float* Wq = (const float*)d_in[3];
    const float* bq = (const float*)d_in[4];
    const float* Wk = (const float*)d_in[5];
    const float* bk = (const float*)d_in[6];
    const float* Wv = (const float*)d_in[7];
    const float* bv = (const float*)d_in[8];
    const float* We = (const float*)d_in[9];
    const float* Ws = (const float*)d_in[10];
    const float* bs = (const float*)d_in[11];
    const float* W1 = (const float*)d_in[12];
    const float* b1 = (const float*)d_in[13];
    const float* W2 = (const float*)d_in[14];
    const float* b2 = (const float*)d_in[15];

    int N = in_sizes[0] / HD;
    int E = in_sizes[1] / 2;

    float* ws = (float*)d_ws;
    size_t nd = (size_t)N * HD;
    float* hbuf = ws;
    float* qbuf = ws + nd;
    float* kbuf = ws + 2 * nd;
    float* vbuf = ws + 3 * nd;
    float* sbuf = ws + 4 * nd;
    float4* meta = (float4*)(ws + 5 * nd);           // E float4
    int* deg    = (int*)(ws + 5 * nd + 4 * (size_t)E);
    int* off    = deg + N;                            // N+1
    int* cursor = off + N + 1;                        // N
    size_t frag_byte = (((5 * nd + 4 * (size_t)E) + (size_t)(3 * N + 1)) * 4 + 15)
                       & ~(size_t)15;
    ushort* Wfrag = (ushort*)((char*)d_ws + frag_byte);

    int gemm_gx = (N + 63) / 64;
    int edge_gx = (E + 255) / 256;
    int attn_gx = (N + 3) / 4;

    // ---- CSR build + weight fragment conversion (once per call) ----
    hipMemsetAsync(deg, 0, (size_t)N * sizeof(int), stream);
    count_deg<<<edge_gx, 256, 0, stream>>>(ei, deg, E);
    scan_kernel<<<1, 1024, 0, stream>>>(deg, off, cursor, N);
    scatter_edges<<<edge_gx, 256, 0, stream>>>(ei, ea, cursor, meta, E);
    conv_w<<<(12 * 8 * 4 * 64 + 255) / 256, 256, 0, stream>>>(Wq, Wk, Wv, Ws, Wfrag);

    for (int l = 0; l < 3; ++l) {
        const float* cur = (l == 0) ? x : hbuf;
        const float* Wel = We + (size_t)l * 2 * HD;

        gemm4_mfma<<<dim3(gemm_gx, 2), 512, 0, stream>>>(
            cur, Wfrag,
            bq + (size_t)l * HD, bk + (size_t)l * HD,
            bv + (size_t)l * HD, bs + (size_t)l * HD,
            qbuf, kbuf, vbuf, sbuf, l, N);

        fused_attn<<<attn_gx, 256, 0, stream>>>(
            qbuf, kbuf, vbuf, sbuf, off, meta, Wel, hbuf, N);
    }

    // head: emb = leaky(h@W1+b1) -> reuse kbuf; logits+log_softmax -> d_out
    emb_kernel<<<(N * CC + 255) / 256, 256, 0, stream>>>(hbuf, W1, b1, kbuf, N);
    logits_kernel<<<(N * 8 + 255) / 256, 256, 0, stream>>>(kbuf, W2, b2, (float*)d_out, N);
}

// Round 9
// 580.670 us; speedup vs baseline: 1.3273x; 1.0485x over previous
//
#include <hip/hip_runtime.h>
#include <hip/hip_bf16.h>
#include <math.h>

#define HD 128   // hidden dim = H*C
#define NH 4     // heads
#define CC 32    // channels per head

typedef __attribute__((ext_vector_type(8))) short short8;
typedef __attribute__((ext_vector_type(4))) float f32x4;

__device__ __forceinline__ float leaky(float x) { return x > 0.f ? x : 0.01f * x; }

// f32 -> bf16 round-to-nearest-even (finite values)
__device__ __forceinline__ ushort bf16_rne(float f) {
    unsigned u = __float_as_uint(f);
    return (ushort)((u + 0x7fffu + ((u >> 16) & 1u)) >> 16);
}
__device__ __forceinline__ float bf16_f(ushort h) {
    return __uint_as_float(((unsigned)h) << 16);
}

// Wfrag layout: [mg(12)][ct(8)][kk(4)][lane(64)][j(8)] ushort, hi half then lo
// half at +WFRAG_HALF. mg = layer*4 + mat. B-frag mapping (16x16x32):
// col = ct*16+(lane&15), k = kk*32+(lane>>4)*8+j.   (verified: r5/r7/r8 passed)
#define WFRAG_HALF (12 * 32 * 64 * 8)

// ---------------------------------------------------------------------------
// Convert W (f32, [3][128][128] x 4 matrices) into bf16 hi/lo B-fragments.
// ---------------------------------------------------------------------------
__global__ __launch_bounds__(256) void conv_w(
    const float* __restrict__ Wq, const float* __restrict__ Wk,
    const float* __restrict__ Wv, const float* __restrict__ Wsk,
    ushort* __restrict__ frag)
{
    int tid = blockIdx.x * 256 + threadIdx.x;
    if (tid >= 12 * 8 * 4 * 64) return;
    int lane = tid & 63;
    int kk = (tid >> 6) & 3;
    int ct = (tid >> 8) & 7;
    int mg = tid >> 11;            // 0..11
    int l = mg >> 2, m = mg & 3;
    const float* src = ((m == 0) ? Wq : (m == 1) ? Wk : (m == 2) ? Wv : Wsk)
                       + (size_t)l * HD * HD;
    int col = ct * 16 + (lane & 15);
    int k0 = kk * 32 + (lane >> 4) * 8;
    ushort* dst = frag + (size_t)tid * 8;
#pragma unroll
    for (int j = 0; j < 8; ++j) {
        float w = src[(size_t)(k0 + j) * HD + col];
        ushort h = bf16_rne(w);
        dst[j] = h;
        dst[WFRAG_HALF + j] = bf16_rne(w - bf16_f(h));
    }
}

// ---------------------------------------------------------------------------
// MFMA GEMM, split-bf16 (hh+hl+lh). 512 threads = 8 waves.
// Block = 64 rows. Wave = (p, h): p in 0..3 owns cols p*32..p*32+31, h in 0..1
// owns rows h*32..h*32+31. W-frags register-resident. Epilogue bounces acc
// through wave-private LDS so stores are full aligned 128B lines (r8 fix).
// ---------------------------------------------------------------------------
__global__ __launch_bounds__(512) void gemm4_mfma(
    const float* __restrict__ X, const ushort* __restrict__ Wfrag,
    const float* __restrict__ bq, const float* __restrict__ bk,
    const float* __restrict__ bv, const float* __restrict__ bsk,
    float* __restrict__ Oq, float* __restrict__ Ok,
    float* __restrict__ Ov, float* __restrict__ Osk,
    int layer, int N)
{
    __shared__ __align__(16) ushort Xh[64 * HD];   // 16 KB
    __shared__ __align__(16) ushort Xl[64 * HD];   // 16 KB
    __shared__ __align__(16) float  Ot[8][16 * 36]; // 18 KB wave-private scratch

    int t = threadIdx.x;
    int row0 = blockIdx.x * 64;

    // ---- stage X tile as hi/lo bf16, swizzled: byte ^= (row&7)<<4 ----
#pragma unroll
    for (int i = 0; i < 4; ++i) {
        int idx = t + i * 512;           // 0..2047
        int r = idx >> 5;                // 0..63
        int c4 = (idx & 31) * 4;         // first k of this float4
        int gr = row0 + r;
        float4 xv = (gr < N) ? *(const float4*)(X + (size_t)gr * HD + c4)
                             : make_float4(0.f, 0.f, 0.f, 0.f);
        ushort h0 = bf16_rne(xv.x), h1 = bf16_rne(xv.y),
               h2 = bf16_rne(xv.z), h3 = bf16_rne(xv.w);
        ushort l0 = bf16_rne(xv.x - bf16_f(h0)), l1 = bf16_rne(xv.y - bf16_f(h1)),
               l2 = bf16_rne(xv.z - bf16_f(h2)), l3 = bf16_rne(xv.w - bf16_f(h3));
        int off = r * 256 + c4 * 2;                 // byte offset, 8B-aligned
        int swz = off ^ ((r & 7) << 4);
        *(ushort4*)((char*)Xh + swz) = make_ushort4(h0, h1, h2, h3);
        *(ushort4*)((char*)Xl + swz) = make_ushort4(l0, l1, l2, l3);
    }
    __syncthreads();

    int w = t >> 6;                  // wave id
    int p = w & 3;                   // col pair: cols p*32..p*32+31
    int h = w >> 2;                  // row half: rows h*32..h*32+31
    int lane = t & 63;
    int col16 = lane & 15;
    int quad = lane >> 4;
    float* scratch = Ot[w];

#pragma unroll
    for (int mm = 0; mm < 2; ++mm) {
        int mat = blockIdx.y * 2 + mm;
        const float* b = (mat == 0) ? bq : (mat == 1) ? bk : (mat == 2) ? bv : bsk;
        float* O = (mat == 0) ? Oq : (mat == 1) ? Ok : (mat == 2) ? Ov : Osk;
        int mg = layer * 4 + mat;

        // ---- load this wave's 2 col-tiles' W fragments into registers ----
        short8 bh[2][4], bl[2][4];
#pragma unroll
        for (int cl = 0; cl < 2; ++cl) {
            int ct = p * 2 + cl;
#pragma unroll
            for (int kk = 0; kk < 4; ++kk) {
                const ushort* wp = Wfrag + ((size_t)((mg * 8 + ct) * 4 + kk) * 64 + lane) * 8;
                bh[cl][kk] = *(const short8*)wp;
                bl[cl][kk] = *(const short8*)(wp + WFRAG_HALF);
            }
        }
        float bcol0 = b[(p * 2 + 0) * 16 + col16];
        float bcol1 = b[(p * 2 + 1) * 16 + col16];

#pragma unroll
        for (int mtl = 0; mtl < 2; ++mtl) {
            int arow = h * 32 + mtl * 16 + col16;    // A row for this lane
            int abase = arow * 256;
            int aswz = (arow & 7) << 4;
            f32x4 c0a = {0.f,0.f,0.f,0.f}, c0b = {0.f,0.f,0.f,0.f}, c0c = {0.f,0.f,0.f,0.f};
            f32x4 c1a = {0.f,0.f,0.f,0.f}, c1b = {0.f,0.f,0.f,0.f}, c1c = {0.f,0.f,0.f,0.f};
#pragma unroll
            for (int kk = 0; kk < 4; ++kk) {
                int koff = abase + kk * 64 + quad * 16;   // bytes
                short8 ah = *(const short8*)((const char*)Xh + (koff ^ aswz));
                short8 al = *(const short8*)((const char*)Xl + (koff ^ aswz));
                c0a = __builtin_amdgcn_mfma_f32_16x16x32_bf16(ah, bh[0][kk], c0a, 0, 0, 0);
                c0b = __builtin_amdgcn_mfma_f32_16x16x32_bf16(ah, bl[0][kk], c0b, 0, 0, 0);
                c0c = __builtin_amdgcn_mfma_f32_16x16x32_bf16(al, bh[0][kk], c0c, 0, 0, 0);
                c1a = __builtin_amdgcn_mfma_f32_16x16x32_bf16(ah, bh[1][kk], c1a, 0, 0, 0);
                c1b = __builtin_amdgcn_mfma_f32_16x16x32_bf16(ah, bl[1][kk], c1b, 0, 0, 0);
                c1c = __builtin_amdgcn_mfma_f32_16x16x32_bf16(al, bh[1][kk], c1c, 0, 0, 0);
            }
            // ---- epilogue via wave-private LDS -> full-line stores ----
#pragma unroll
            for (int i = 0; i < 4; ++i) {
                int rr = quad * 4 + i;
                scratch[rr * 36 + col16]      = c0a[i] + c0b[i] + c0c[i] + bcol0;
                scratch[rr * 36 + 16 + col16] = c1a[i] + c1b[i] + c1c[i] + bcol1;
            }
#pragma unroll
            for (int s = 0; s < 2; ++s) {
                int row = s * 8 + (lane >> 3);
                int c4 = (lane & 7) * 4;
                float4 v = *(const float4*)(&scratch[row * 36 + c4]);
                int gr = row0 + h * 32 + mtl * 16 + row;
                if (gr < N)
                    *(float4*)(O + (size_t)gr * HD + p * 32 + c4) = v;
            }
        }
    }
}

// ---------------------------------------------------------------------------
// CSR build step 1: deg[dst]++ per edge
// ---------------------------------------------------------------------------
__global__ __launch_bounds__(256) void count_deg(
    const int* __restrict__ ei, int* __restrict__ deg, int E)
{
    int e = blockIdx.x * 256 + threadIdx.x;
    if (e < E) atomicAdd(&deg[ei[E + e]], 1);
}

// ---------------------------------------------------------------------------
// CSR build step 2: exclusive scan of deg -> off (N+1), duplicate into cursor.
// ---------------------------------------------------------------------------
__global__ __launch_bounds__(1024) void scan_kernel(
    const int* __restrict__ deg, int* __restrict__ off,
    int* __restrict__ cursor, int N)
{
    __shared__ int wsum[16];
    __shared__ int carry_s;
    int tid = threadIdx.x;
    int lane = tid & 63;
    int w = tid >> 6;
    if (tid == 0) carry_s = 0;
    __syncthreads();
    for (int base = 0; base < N; base += 1024) {
        int idx = base + tid;
        int x = (idx < N) ? deg[idx] : 0;
        int val = x;
#pragma unroll
        for (int s = 1; s < 64; s <<= 1) {
            int t = __shfl_up(val, s);
            if (lane >= s) val += t;
        }
        if (lane == 63) wsum[w] = val;
        __syncthreads();
        if (w == 0) {
            int t = (lane < 16) ? wsum[lane] : 0;
#pragma unroll
            for (int s = 1; s < 16; s <<= 1) {
                int u = __shfl_up(t, s);
                if (lane >= s) t += u;
            }
            if (lane < 16) wsum[lane] = t;  // inclusive wave totals
        }
        __syncthreads();
        int carry = carry_s;
        int wexcl = (w > 0) ? wsum[w - 1] : 0;
        int excl = carry + wexcl + (val - x);
        if (idx < N) { off[idx] = excl; cursor[idx] = excl; }
        __syncthreads();
        if (tid == 0) carry_s = carry + wsum[15];
        __syncthreads();
    }
    if (threadIdx.x == 0) off[N] = carry_s;
}

// ---------------------------------------------------------------------------
// CSR build step 3: scatter edge meta {src, ea0, ea1} into dst-grouped slots
// ---------------------------------------------------------------------------
__global__ __launch_bounds__(256) void scatter_edges(
    const int* __restrict__ ei, const float* __restrict__ ea,
    int* __restrict__ cursor, float4* __restrict__ meta, int E)
{
    int e = blockIdx.x * 256 + threadIdx.x;
    if (e >= E) return;
    int dst = ei[E + e];
    int pos = atomicAdd(&cursor[dst], 1);
    meta[pos] = make_float4(__int_as_float(ei[e]), ea[2 * e], ea[2 * e + 1], 0.f);
}

// ---------------------------------------------------------------------------
// Fused attention v2: one wave per dst node, TWO edges in flight.
// Halves (lanes 0-31 / 32-63) process alternate edges; each half runs an
// independent online softmax (sentinel m=-1e30 handles empty halves / deg-0
// exactly: scale underflows to 0, deg-0 emits skip-only). float4/lane: one
// load instruction = full 512B k/v row. Head reduce = 3 shfl_xor (bits 0-2,
// halves never mix). Final merge across halves via shfl_xor(...,32).
// ---------------------------------------------------------------------------
__global__ __launch_bounds__(256) void fused_attn(
    const float* __restrict__ q, const float* __restrict__ k,
    const float* __restrict__ v, const float* __restrict__ skip,
    const int* __restrict__ off, const float4* __restrict__ meta,
    const float* __restrict__ We, float* __restrict__ hout, int N)
{
    int wid = (int)((blockIdx.x * 256 + threadIdx.x) >> 6);  // dst node
    int lane = threadIdx.x & 63;
    if (wid >= N) return;
    int half = lane >> 5;
    int li = lane & 31;
    int c4 = li * 4;                 // 4 channels per lane

    float4 w0 = *(const float4*)(We + c4);        // We row 0
    float4 w1 = *(const float4*)(We + HD + c4);   // We row 1
    float4 q4 = *(const float4*)(q + (size_t)wid * HD + c4);

    float m = -1e30f, s = 0.f;
    float4 o = make_float4(0.f, 0.f, 0.f, 0.f);

    int beg = off[wid], end = off[wid + 1];
    for (int j = beg + half; j < end; j += 2) {
        float4 md = meta[j];
        int src = __float_as_int(md.x);
        float4 e;
        e.x = md.y * w0.x + md.z * w1.x;
        e.y = md.y * w0.y + md.z * w1.y;
        e.z = md.y * w0.z + md.z * w1.z;
        e.w = md.y * w0.w + md.z * w1.w;
        float4 kv = *(const float4*)(k + (size_t)src * HD + c4);
        float4 vv = *(const float4*)(v + (size_t)src * HD + c4);
        float p = q4.x * (kv.x + e.x) + q4.y * (kv.y + e.y)
                + q4.z * (kv.z + e.z) + q4.w * (kv.w + e.w);
        p += __shfl_xor(p, 1);
        p += __shfl_xor(p, 2);
        p += __shfl_xor(p, 4);       // now all 8 lanes of this head agree
        p *= 0.17677669529663687f;   // 1/sqrt(32)
        float mn = fmaxf(m, p);
        float scale = __expf(m - mn);
        float pe = __expf(p - mn);
        s = s * scale + pe;
        o.x = o.x * scale + pe * (vv.x + e.x);
        o.y = o.y * scale + pe * (vv.y + e.y);
        o.z = o.z * scale + pe * (vv.z + e.z);
        o.w = o.w * scale + pe * (vv.w + e.w);
        m = mn;
    }

    // ---- merge the two half-wave softmax states ----
    float mo = __shfl_xor(m, 32);
    float so = __shfl_xor(s, 32);
    float4 oo;
    oo.x = __shfl_xor(o.x, 32);
    oo.y = __shfl_xor(o.y, 32);
    oo.z = __shfl_xor(o.z, 32);
    oo.w = __shfl_xor(o.w, 32);
    float mm = fmaxf(m, mo);
    float sa = __expf(m - mm);       // empty half: exp(-1e30-mm) = 0
    float sb = __expf(mo - mm);
    float stot = s * sa + so * sb;
    float inv = 1.f / (stot + 1e-16f);

    if (half == 0) {
        float4 sk = *(const float4*)(skip + (size_t)wid * HD + c4);
        float4 hv;
        hv.x = leaky((o.x * sa + oo.x * sb) * inv + sk.x);
        hv.y = leaky((o.y * sa + oo.y * sb) * inv + sk.y);
        hv.z = leaky((o.z * sa + oo.z * sb) * inv + sk.z);
        hv.w = leaky((o.w * sa + oo.w * sb) * inv + sk.w);
        *(float4*)(hout + (size_t)wid * HD + c4) = hv;
    }
}

// ---------------------------------------------------------------------------
// emb = leaky(h @ W1 + b1)   (N x 128 @ 128 x 32)
// ---------------------------------------------------------------------------
__global__ __launch_bounds__(256) void emb_kernel(
    const float* __restrict__ h, const float* __restrict__ W1,
    const float* __restrict__ b1, float* __restrict__ emb, int N)
{
    int i = blockIdx.x * 256 + threadIdx.x;
    if (i >= N * CC) return;
    int row = i >> 5, col = i & 31;
    const float* hr = h + (size_t)row * HD;
    float acc = 0.f;
#pragma unroll 4
    for (int k = 0; k < HD; ++k) acc += hr[k] * W1[k * CC + col];
    emb[i] = leaky(acc + b1[col]);
}

// ---------------------------------------------------------------------------
// logits = emb @ W2 + b2; out = log_softmax(logits) per row (8 cols).
// ---------------------------------------------------------------------------
__global__ __launch_bounds__(256) void logits_kernel(
    const float* __restrict__ emb, const float* __restrict__ W2,
    const float* __restrict__ b2, float* __restrict__ out, int N)
{
    int i = blockIdx.x * 256 + threadIdx.x;
    int row = i >> 3, col = i & 7;
    if (row >= N) return;
    const float* er = emb + (size_t)row * CC;
    float acc = b2[col];
#pragma unroll
    for (int k = 0; k < CC; ++k) acc += er[k] * W2[k * 8 + col];
    float mx = acc;
    mx = fmaxf(mx, __shfl_xor(mx, 1));
    mx = fmaxf(mx, __shfl_xor(mx, 2));
    mx = fmaxf(mx, __shfl_xor(mx, 4));
    float ex = expf(acc - mx);
    float sm = ex;
    sm += __shfl_xor(sm, 1);
    sm += __shfl_xor(sm, 2);
    sm += __shfl_xor(sm, 4);
    out[i] = acc - mx - logf(sm);
}

extern "C" void kernel_launch(void* const* d_in, const int* in_sizes, int n_in,
                              void* d_out, int out_size, void* d_ws, size_t ws_size,
                              hipStream_t stream)
{
    const float* x  = (const float*)d_in[0];
    const int*   ei = (const int*)d_in[1];
    const float* ea = (const float*)d_in[2];
    const float* Wq = (const float*)d_in[3];
    const float* bq = (const float*)d_in[4];
    const float* Wk = (const float*)d_in[5];
    const float* bk = (const float*)d_in[6];
    const float* Wv = (const float*)d_in[7];
    const float* bv = (const float*)d_in[8];
    const float* We = (const float*)d_in[9];
    const float* Ws = (const float*)d_in[10];
    const float* bs = (const float*)d_in[11];
    const float* W1 = (const float*)d_in[12];
    const float* b1 = (const float*)d_in[13];
    const float* W2 = (const float*)d_in[14];
    const float* b2 = (const float*)d_in[15];

    int N = in_sizes[0] / HD;
    int E = in_sizes[1] / 2;

    float* ws = (float*)d_ws;
    size_t nd = (size_t)N * HD;
    float* hbuf = ws;
    float* qbuf = ws + nd;
    float* kbuf = ws + 2 * nd;
    float* vbuf = ws + 3 * nd;
    float* sbuf = ws + 4 * nd;
    float4* meta = (float4*)(ws + 5 * nd);           // E float4
    int* deg    = (int*)(ws + 5 * nd + 4 * (size_t)E);
    int* off    = deg + N;                            // N+1
    int* cursor = off + N + 1;                        // N
    size_t frag_byte = (((5 * nd + 4 * (size_t)E) + (size_t)(3 * N + 1)) * 4 + 15)
                       & ~(size_t)15;
    ushort* Wfrag = (ushort*)((char*)d_ws + frag_byte);

    int gemm_gx = (N + 63) / 64;
    int edge_gx = (E + 255) / 256;
    int attn_gx = (N + 3) / 4;

    // ---- CSR build + weight fragment conversion (once per call) ----
    hipMemsetAsync(deg, 0, (size_t)N * sizeof(int), stream);
    count_deg<<<edge_gx, 256, 0, stream>>>(ei, deg, E);
    scan_kernel<<<1, 1024, 0, stream>>>(deg, off, cursor, N);
    scatter_edges<<<edge_gx, 256, 0, stream>>>(ei, ea, cursor, meta, E);
    conv_w<<<(12 * 8 * 4 * 64 + 255) / 256, 256, 0, stream>>>(Wq, Wk, Wv, Ws, Wfrag);

    for (int l = 0; l < 3; ++l) {
        const float* cur = (l == 0) ? x : hbuf;
        const float* Wel = We + (size_t)l * 2 * HD;

        gemm4_mfma<<<dim3(gemm_gx, 2), 512, 0, stream>>>(
            cur, Wfrag,
            bq + (size_t)l * HD, bk + (size_t)l * HD,
            bv + (size_t)l * HD, bs + (size_t)l * HD,
            qbuf, kbuf, vbuf, sbuf, l, N);

        fused_attn<<<attn_gx, 256, 0, stream>>>(
            qbuf, kbuf, vbuf, sbuf, off, meta, Wel, hbuf, N);
    }

    // head: emb = leaky(h@W1+b1) -> reuse kbuf; logits+log_softmax -> d_out
    emb_kernel<<<(N * CC + 255) / 256, 256, 0, stream>>>(hbuf, W1, b1, kbuf, N);
    logits_kernel<<<(N * 8 + 255) / 256, 256, 0, stream>>>(kbuf, W2, b2, (float*)d_out, N);
}